// Round 1
// baseline (162.469 us; speedup 1.0000x reference)
//
#include <hip/hip_runtime.h>
#include <hip/hip_bf16.h>

// Problem: B=8, C=DIM=64, H=W=64 -> pooled 32x32 (N=1024 tokens), 16 heads x d=4.
// ws layout (floats): t[524288] | idx[524288 ints] | q[524288] | k[524288] | v[524288] | o[524288]
// q/k/v layout: (B, H=16, N=1024, D=4) contiguous -> per (b,h) a 4096-float slab.

// ---------------- Kernel A: 2x2 maxpool + argmax ----------------
__global__ __launch_bounds__(256) void pool_kernel(const float* __restrict__ x,
                                                   float* __restrict__ t,
                                                   int* __restrict__ idx) {
    int g = blockIdx.x * 256 + threadIdx.x;            // covers 8*64*32*32 = 524288
    int wp = g & 31, hp = (g >> 5) & 31, c = (g >> 10) & 63, b = g >> 16;
    const float* px = x + (((b * 64 + c) * 64 + 2 * hp) * 64 + 2 * wp);
    float v0 = px[0], v1 = px[1], v2 = px[64], v3 = px[65];
    float best = v0; int bi = 0;                        // first-max semantics (strict >)
    if (v1 > best) { best = v1; bi = 1; }
    if (v2 > best) { best = v2; bi = 2; }
    if (v3 > best) { best = v3; bi = 3; }
    int n = hp * 32 + wp;
    t[(b * 1024 + n) * 64 + c] = best;
    idx[g] = bi;                                        // layout (b,c,hp,wp)
}

// ---------------- Kernel B: qkv = t @ w_qkv, scatter to (B,H,N,4) ----------------
__global__ __launch_bounds__(192) void qkv_kernel(const float* __restrict__ t,
                                                  const float* __restrict__ w_qkv,
                                                  float* __restrict__ q,
                                                  float* __restrict__ k,
                                                  float* __restrict__ v) {
    __shared__ float trow[16 * 64];                     // 16 token rows
    int tid = threadIdx.x;                              // 0..191 (j = output column)
    int row0 = blockIdx.x * 16;
    for (int i = tid; i < 1024; i += 192) trow[i] = t[row0 * 64 + i];
    float wcol[64];                                     // my w_qkv column, in registers
    #pragma unroll
    for (int c = 0; c < 64; c++) wcol[c] = w_qkv[c * 192 + tid];
    __syncthreads();
    int s = tid >> 6, h = (tid >> 2) & 15, d = tid & 3;
    float* dst = (s == 0) ? q : (s == 1) ? k : v;
    for (int r = 0; r < 16; r++) {
        const float4* tr = (const float4*)&trow[r * 64];
        float acc = 0.f;
        #pragma unroll
        for (int c4 = 0; c4 < 16; c4++) {
            float4 tv = tr[c4];                         // LDS broadcast (all lanes same addr)
            acc += tv.x * wcol[c4 * 4] + tv.y * wcol[c4 * 4 + 1]
                 + tv.z * wcol[c4 * 4 + 2] + tv.w * wcol[c4 * 4 + 3];
        }
        int ng = row0 + r, b = ng >> 10, n = ng & 1023;
        dst[((b * 16 + h) * 1024 + n) * 4 + d] = acc;
    }
}

// ---------------- Kernel C: flash-style attention, one q row per thread ----------------
// grid = 128 (b,h) * 4 q-chunks; K,V fully resident in LDS (32 KB).
// Scores bounded (~|s|<20 << 88) so exp without max-subtract is safe; softmax is
// shift-invariant so the result is identical to the reference.
__global__ __launch_bounds__(256) void attn_kernel(const float* __restrict__ q,
                                                   const float* __restrict__ k,
                                                   const float* __restrict__ v,
                                                   float* __restrict__ o) {
    __shared__ float4 kvs[2048];                        // [0,1024) = K, [1024,2048) = V
    int bh = blockIdx.x >> 2, chunk = blockIdx.x & 3;
    int tid = threadIdx.x;
    const float4* kp = (const float4*)(k + bh * 4096);
    const float4* vp = (const float4*)(v + bh * 4096);
    for (int i = tid; i < 1024; i += 256) { kvs[i] = kp[i]; kvs[1024 + i] = vp[i]; }
    __syncthreads();
    int row = chunk * 256 + tid;
    float4 qv = ((const float4*)(q + bh * 4096))[row];
    const float C1 = 0.5f * 1.44269504088896f;          // scale * log2(e), folded into q
    float qx = qv.x * C1, qy = qv.y * C1, qz = qv.z * C1, qw = qv.w * C1;
    float l = 0.f, ax = 0.f, ay = 0.f, az = 0.f, aw = 0.f;
    #pragma unroll 8
    for (int key = 0; key < 1024; key++) {
        float4 kk = kvs[key];                           // broadcast read: conflict-free
        float s = qx * kk.x + qy * kk.y + qz * kk.z + qw * kk.w;
        float p = __builtin_exp2f(s);                   // native v_exp_f32
        float4 vv = kvs[1024 + key];
        l += p;
        ax += p * vv.x; ay += p * vv.y; az += p * vv.z; aw += p * vv.w;
    }
    float rl = 1.f / l;
    int b = bh >> 4, h = bh & 15;
    float4 res = { ax * rl, ay * rl, az * rl, aw * rl };
    *(float4*)&o[(b * 1024 + row) * 64 + h * 4] = res;  // (B,N,64), 16B aligned
}

// ---------------- Kernel D: o @ w_proj + BN + max-unpool scatter ----------------
// grid = B*Hp = 256 blocks; thread = (cg, wp); writes every output element (0 or val),
// so no prior memset of d_out is needed.
__global__ __launch_bounds__(256) void proj_kernel(const float* __restrict__ o,
                                                   const float* __restrict__ w_proj,
                                                   const float* __restrict__ gamma,
                                                   const float* __restrict__ beta,
                                                   const float* __restrict__ mean,
                                                   const float* __restrict__ var,
                                                   const int* __restrict__ idx,
                                                   float* __restrict__ out) {
    __shared__ float ws[64 * 64];                       // w_proj
    int b = blockIdx.x >> 5, hp = blockIdx.x & 31;
    int tid = threadIdx.x;
    for (int i = tid; i < 4096; i += 256) ws[i] = w_proj[i];
    int wp = tid & 31, cg = tid >> 5;                   // 8 c-groups x 32 wp
    float oreg[64];                                     // my o row in registers
    const float* orow = o + (b * 1024 + hp * 32 + wp) * 64;
    #pragma unroll
    for (int a4 = 0; a4 < 16; a4++) {
        float4 t4 = ((const float4*)orow)[a4];
        oreg[a4 * 4] = t4.x; oreg[a4 * 4 + 1] = t4.y;
        oreg[a4 * 4 + 2] = t4.z; oreg[a4 * 4 + 3] = t4.w;
    }
    __syncthreads();
    #pragma unroll
    for (int cc = 0; cc < 8; cc++) {
        int c = cg + 8 * cc;                            // 8 distinct banks -> conflict-free
        float acc = 0.f;
        #pragma unroll
        for (int a = 0; a < 64; a++) acc += oreg[a] * ws[a * 64 + c];
        float inv = gamma[c] * rsqrtf(var[c] + 1e-5f);
        float val = acc * inv + (beta[c] - mean[c] * inv);
        int id = idx[((b * 64 + c) * 32 + hp) * 32 + wp];
        int base = ((b * 64 + c) * 64 + 2 * hp) * 64 + 2 * wp;
        float2 r0 = { id == 0 ? val : 0.f, id == 1 ? val : 0.f };
        float2 r1 = { id == 2 ? val : 0.f, id == 3 ? val : 0.f };
        *(float2*)&out[base] = r0;                      // row 2hp,   cols 2wp..2wp+1
        *(float2*)&out[base + 64] = r1;                 // row 2hp+1
    }
}

extern "C" void kernel_launch(void* const* d_in, const int* in_sizes, int n_in,
                              void* d_out, int out_size, void* d_ws, size_t ws_size,
                              hipStream_t stream) {
    const float* x      = (const float*)d_in[0];
    const float* w_qkv  = (const float*)d_in[1];
    const float* w_proj = (const float*)d_in[2];
    const float* gamma  = (const float*)d_in[3];
    const float* beta   = (const float*)d_in[4];
    const float* bn_mean= (const float*)d_in[5];
    const float* bn_var = (const float*)d_in[6];
    float* out = (float*)d_out;

    const int SEG = 524288;                             // 8*1024*64
    float* ws = (float*)d_ws;
    float* t   = ws;
    int*   idx = (int*)(ws + SEG);
    float* q   = ws + 2 * SEG;
    float* k   = ws + 3 * SEG;
    float* v   = ws + 4 * SEG;
    float* o   = ws + 5 * SEG;

    pool_kernel<<<2048, 256, 0, stream>>>(x, t, idx);
    qkv_kernel<<<512, 192, 0, stream>>>(t, w_qkv, q, k, v);
    attn_kernel<<<512, 256, 0, stream>>>(q, k, v, o);
    proj_kernel<<<256, 256, 0, stream>>>(o, w_proj, gamma, beta, bn_mean, bn_var, idx, out);
}